// Round 2
// baseline (127.879 us; speedup 1.0000x reference)
//
#include <hip/hip_runtime.h>
#include <hip/hip_bf16.h>

// Disable FMA contraction globally: the coordinate transform
// (p+1)*scale-0.5 must round exactly like numpy float32, or floor()
// can flip a cell index and change which octree keys we look up.
#pragma clang fp contract(off)

#define K_BITS 18        // bucket table: 2^18 buckets over the keyspace
#define MAX_KEY_BITS 26  // bitmap sized for keys < 2^26 (depth=8, B=4)

// ---------------------------------------------------------------------------
// Kernel A: init workspace. bmp = 0, tab = H (prefill; scatter overwrites
// every bucket <= last key's bucket, the tail keeps H = lower_bound past end).
// ---------------------------------------------------------------------------
__global__ __launch_bounds__(256) void octi_init(
    unsigned* __restrict__ bmp, int* __restrict__ tab,
    int WB, int NB1, int H) {
  int j = blockIdx.x * 256 + threadIdx.x;
  if (j < WB) bmp[j] = 0u;
  if (j < NB1) tab[j] = H;
}

// ---------------------------------------------------------------------------
// Kernel B: one streaming pass over sorted keys builds BOTH
//   - presence bitmap (atomicOr)
//   - exact lower_bound bucket table: thread m owns buckets
//     (keys[m-1]>>S, keys[m]>>S]  (thread 0: [0, keys[0]>>S])
// ---------------------------------------------------------------------------
__global__ __launch_bounds__(256) void octi_scatter(
    const int* __restrict__ keys, int H, const int* __restrict__ depth_ptr,
    unsigned* __restrict__ bmp, int* __restrict__ tab) {
  int m = blockIdx.x * 256 + threadIdx.x;
  if (m >= H) return;
  int depth = *depth_ptr;
  int kb = 3 * depth + 2;
  int S = kb > K_BITS ? kb - K_BITS : 0;
  unsigned k = (unsigned)keys[m];
  if (bmp && kb <= MAX_KEY_BITS)
    atomicOr(&bmp[k >> 5], 1u << (k & 31));
  int bc = (int)(k >> S);
  int bp = (m == 0) ? -1 : (int)(((unsigned)keys[m - 1]) >> S);
  for (int j = bp + 1; j <= bc; ++j) tab[j] = m;  // disjoint ranges, no race
}

// ---------------------------------------------------------------------------
// Kernel C: main interpolation, C == 32 fast path.
// 8 lanes per point: lane = corner index (search phase) and
// channel-quad index (gather/write phase, float4 each).
// ---------------------------------------------------------------------------
__global__ __launch_bounds__(256) void octi_interp32(
    const float* __restrict__ data, const float* __restrict__ pts,
    const int* __restrict__ keys, const int* __restrict__ depth_ptr,
    const int* __restrict__ tab, const unsigned* __restrict__ bmp,
    float* __restrict__ out, int N, int H) {
  int t = blockIdx.x * 256 + threadIdx.x;
  int i = t >> 3;   // point index
  if (i >= N) return;
  int l = t & 7;    // corner / channel-quad index

  int depth = *depth_ptr;
  int kb = 3 * depth + 2;
  int S = kb > K_BITS ? kb - K_BITS : 0;
  float scale = (float)(1 << (depth - 1));

  float4 p = reinterpret_cast<const float4*>(pts)[i];

  // exact numpy-f32 sequence: (p + 1.0f) * scale - 0.5f  (no contraction)
  float xf = (p.x + 1.0f) * scale - 0.5f;
  float yf = (p.y + 1.0f) * scale - 0.5f;
  float zf = (p.z + 1.0f) * scale - 0.5f;
  float xi = floorf(xf), yi = floorf(yf), zi = floorf(zf);
  float fx = xf - xi, fy = yf - yi, fz = zf - zi;

  // grid row order: corner = (gx<<2)|(gy<<1)|gz
  int gx = (l >> 2) & 1, gy = (l >> 1) & 1, gz = l & 1;
  int ix = (int)xi + gx;
  int iy = (int)yi + gy;
  int iz = (int)zi + gz;
  int b = (int)p.w;

  // Morton key, identical bit ops to the reference (arithmetic >> handles -1)
  int key = b << (3 * depth);
  #pragma unroll 8
  for (int d = 0; d < depth; ++d) {
    key |= ((ix >> d) & 1) << (3 * d + 2);
    key |= ((iy >> d) & 1) << (3 * d + 1);
    key |= ((iz >> d) & 1) << (3 * d);
  }

  bool present;
  int posc = 0;
  if (bmp && kb <= MAX_KEY_BITS) {
    // one random load decides; ~97% of corners stop here
    unsigned uk = (unsigned)key;
    present = (bmp[uk >> 5] >> (uk & 31)) & 1u;
    if (present) {
      unsigned bkt = uk >> S;
      int lo = tab[bkt], hi = tab[bkt + 1];
      while (lo < hi) {
        int mid = (lo + hi) >> 1;
        if (keys[mid] < key) lo = mid + 1; else hi = mid;
      }
      posc = lo;  // present => exact match, lo < H, keys[lo]==key
    }
  } else {
    int lo = 0, hi = H;
    if (tab) {
      unsigned bkt = ((unsigned)key) >> S;
      lo = tab[bkt];
      hi = tab[bkt + 1];
    }
    while (lo < hi) {
      int mid = (lo + hi) >> 1;
      if (keys[mid] < key) lo = mid + 1; else hi = mid;
    }
    posc = min(lo, H - 1);
    present = (keys[posc] == key);
  }

  // trilinear weight |((1-gx)-fx) * ((1-gy)-fy) * ((1-gz)-fz)|
  float wx = (1.0f - (float)gx) - fx;
  float wy = (1.0f - (float)gy) - fy;
  float wz = (1.0f - (float)gz) - fz;
  float w = present ? fabsf((wx * wy) * wz) : 0.0f;

  // exchange (w, pos) across the aligned 8-lane group; accumulate float4
  int lane = threadIdx.x & 63;
  int base = lane & 56;
  float4 acc = make_float4(0.f, 0.f, 0.f, 0.f);
  float norm = 0.0f;
  #pragma unroll
  for (int q = 0; q < 8; ++q) {
    float wq = __shfl(w, base + q, 64);
    int   pq = __shfl(posc, base + q, 64);
    norm += wq;
    if (wq != 0.0f) {  // skip gather when weight is exactly 0 (identical math)
      float4 f = reinterpret_cast<const float4*>(data)[pq * 8 + l];
      acc.x += wq * f.x;
      acc.y += wq * f.y;
      acc.z += wq * f.z;
      acc.w += wq * f.w;
    }
  }
  float dnm = norm + 1e-12f;
  float4 o = make_float4(acc.x / dnm, acc.y / dnm, acc.z / dnm, acc.w / dnm);
  reinterpret_cast<float4*>(out)[i * 8 + l] = o;
}

// ---------------------------------------------------------------------------
// Generic-C fallback (defensive; reference uses C=32 so this should not run)
// ---------------------------------------------------------------------------
__global__ __launch_bounds__(256) void octi_interp_gen(
    const float* __restrict__ data, const float* __restrict__ pts,
    const int* __restrict__ keys, const int* __restrict__ depth_ptr,
    const int* __restrict__ tab, const unsigned* __restrict__ bmp,
    float* __restrict__ out, int N, int H, int C) {
  int i = blockIdx.x * 256 + threadIdx.x;
  if (i >= N) return;
  int depth = *depth_ptr;
  int kb = 3 * depth + 2;
  int S = kb > K_BITS ? kb - K_BITS : 0;
  float scale = (float)(1 << (depth - 1));
  float4 p = reinterpret_cast<const float4*>(pts)[i];
  float xf = (p.x + 1.0f) * scale - 0.5f;
  float yf = (p.y + 1.0f) * scale - 0.5f;
  float zf = (p.z + 1.0f) * scale - 0.5f;
  float xi = floorf(xf), yi = floorf(yf), zi = floorf(zf);
  float fx = xf - xi, fy = yf - yi, fz = zf - zi;
  int b = (int)p.w;
  float wv[8]; int pv[8];
  float norm = 0.0f;
  for (int l = 0; l < 8; ++l) {
    int gx = (l >> 2) & 1, gy = (l >> 1) & 1, gz = l & 1;
    int ix = (int)xi + gx, iy = (int)yi + gy, iz = (int)zi + gz;
    int key = b << (3 * depth);
    for (int d = 0; d < depth; ++d) {
      key |= ((ix >> d) & 1) << (3 * d + 2);
      key |= ((iy >> d) & 1) << (3 * d + 1);
      key |= ((iz >> d) & 1) << (3 * d);
    }
    bool present; int posc = 0;
    if (bmp && kb <= MAX_KEY_BITS) {
      unsigned uk = (unsigned)key;
      present = (bmp[uk >> 5] >> (uk & 31)) & 1u;
      if (present) {
        unsigned bkt = uk >> S;
        int lo = tab[bkt], hi = tab[bkt + 1];
        while (lo < hi) { int mid = (lo + hi) >> 1; if (keys[mid] < key) lo = mid + 1; else hi = mid; }
        posc = lo;
      }
    } else {
      int lo = 0, hi = H;
      if (tab) { unsigned bkt = ((unsigned)key) >> S; lo = tab[bkt]; hi = tab[bkt + 1]; }
      while (lo < hi) { int mid = (lo + hi) >> 1; if (keys[mid] < key) lo = mid + 1; else hi = mid; }
      posc = min(lo, H - 1);
      present = (keys[posc] == key);
    }
    float wx = (1.0f - (float)gx) - fx;
    float wy = (1.0f - (float)gy) - fy;
    float wz = (1.0f - (float)gz) - fz;
    float w = present ? fabsf((wx * wy) * wz) : 0.0f;
    wv[l] = w; pv[l] = posc; norm += w;
  }
  float dnm = norm + 1e-12f;
  for (int c = 0; c < C; ++c) {
    float acc = 0.0f;
    for (int q = 0; q < 8; ++q)
      if (wv[q] != 0.0f) acc += wv[q] * data[(long long)pv[q] * C + c];
    out[(long long)i * C + c] = acc / dnm;
  }
}

extern "C" void kernel_launch(void* const* d_in, const int* in_sizes, int n_in,
                              void* d_out, int out_size, void* d_ws, size_t ws_size,
                              hipStream_t stream) {
  const float* data = (const float*)d_in[0];
  const float* pts  = (const float*)d_in[1];
  const int*   keys = (const int*)d_in[2];
  const int*   dep  = (const int*)d_in[3];
  float* out = (float*)d_out;

  int H = in_sizes[2];
  int N = in_sizes[1] / 4;
  int C = (H > 0) ? in_sizes[0] / H : 0;

  const int NB = 1 << K_BITS;
  const int WB = 1 << (MAX_KEY_BITS - 5);  // bitmap words (8 MB)
  size_t tab_bytes = (size_t)(NB + 1) * sizeof(int);
  size_t need_bmp = tab_bytes + (size_t)WB * sizeof(unsigned);

  int* tab = (int*)d_ws;
  unsigned* bmp = (unsigned*)((char*)d_ws + tab_bytes);
  bool useTab = ws_size >= tab_bytes;
  bool useBmp = ws_size >= need_bmp;

  if (useTab) {
    int initThreads = useBmp ? max(WB, NB + 1) : (NB + 1);
    octi_init<<<(initThreads + 255) / 256, 256, 0, stream>>>(
        useBmp ? bmp : nullptr, tab, useBmp ? WB : 0, NB + 1, H);
    octi_scatter<<<(H + 255) / 256, 256, 0, stream>>>(
        keys, H, dep, useBmp ? bmp : nullptr, tab);
  }

  if (C == 32) {
    long long tt = (long long)N * 8;
    int blocks = (int)((tt + 255) / 256);
    octi_interp32<<<blocks, 256, 0, stream>>>(
        data, pts, keys, dep, useTab ? tab : nullptr,
        (useTab && useBmp) ? bmp : nullptr, out, N, H);
  } else {
    int blocks = (N + 255) / 256;
    octi_interp_gen<<<blocks, 256, 0, stream>>>(
        data, pts, keys, dep, useTab ? tab : nullptr,
        (useTab && useBmp) ? bmp : nullptr, out, N, H, C);
  }
}

// Round 3
// 101.180 us; speedup vs baseline: 1.2639x; 1.2639x over previous
//
#include <hip/hip_runtime.h>
#include <hip/hip_bf16.h>

// Disable FMA contraction globally: the coordinate transform
// (p+1)*scale-0.5 must round exactly like numpy float32, or floor()
// can flip a cell index and change which octree keys we look up.
#pragma clang fp contract(off)

#define K_BITS 18      // fallback bucket bits (1 MB table)
#define K_BITS_BIG 21  // preferred bucket bits (8 MB table, ~1 key/bucket)

typedef float f32x4 __attribute__((ext_vector_type(4)));

// Morton bit-spread of the low (up to 10) bits of v: bit d -> bit 3d.
// Bit-exact with the reference loop: (v>>d)&1 for d in [0,depth) is
// identical to spreading (v & ((1<<depth)-1)), incl. negative v (two's
// complement: -1 -> all depth bits set) and overflow v=2^depth -> 0.
__device__ __forceinline__ unsigned morton_spread(unsigned v) {
  v = (v | (v << 16)) & 0x030000FFu;
  v = (v | (v << 8)) & 0x0300F00Fu;
  v = (v | (v << 4)) & 0x030C30C3u;
  v = (v | (v << 2)) & 0x09249249u;
  return v;
}

// ---------------------------------------------------------------------------
// Kernel A: prefill tab with H (tail buckets past the last key keep H,
// the exact lower_bound for "past end").
// ---------------------------------------------------------------------------
__global__ __launch_bounds__(256) void octi_init(
    int* __restrict__ tab, int NB1, int H) {
  int j = blockIdx.x * 256 + threadIdx.x;
  if (j < NB1) tab[j] = H;
}

// ---------------------------------------------------------------------------
// Kernel B: streaming scatter builds the exact lower_bound bucket table.
// Thread m owns buckets (keys[m-1]>>S, keys[m]>>S]  (thread 0: [0, keys[0]>>S]).
// Disjoint ranges -> no races, no atomics.
// ---------------------------------------------------------------------------
__global__ __launch_bounds__(256) void octi_scatter(
    const int* __restrict__ keys, int H, const int* __restrict__ depth_ptr,
    int* __restrict__ tab, int kbits) {
  int m = blockIdx.x * 256 + threadIdx.x;
  if (m >= H) return;
  int depth = *depth_ptr;
  int kb = 3 * depth + 2;
  int S = kb > kbits ? kb - kbits : 0;
  int bc = (int)(((unsigned)keys[m]) >> S);
  int bp = (m == 0) ? -1 : (int)(((unsigned)keys[m - 1]) >> S);
  for (int j = bp + 1; j <= bc; ++j) tab[j] = m;
}

// ---------------------------------------------------------------------------
// Kernel C: main interpolation, C == 32 fast path.
// 8 lanes per point: lane = corner index (search phase) and
// channel-quad index (gather/write phase, float4 each).
// ---------------------------------------------------------------------------
__global__ __launch_bounds__(256) void octi_interp32(
    const float* __restrict__ data, const float* __restrict__ pts,
    const int* __restrict__ keys, const int* __restrict__ depth_ptr,
    const int* __restrict__ tab, float* __restrict__ out,
    int N, int H, int kbits) {
  int t = blockIdx.x * 256 + threadIdx.x;
  int i = t >> 3;   // point index
  if (i >= N) return;
  int l = t & 7;    // corner / channel-quad index

  int depth = *depth_ptr;
  int kb = 3 * depth + 2;
  int S = kb > kbits ? kb - kbits : 0;
  float scale = (float)(1 << (depth - 1));
  unsigned cmask = (1u << depth) - 1u;

  // streaming read: non-temporal, keep L2 for keys/tab
  f32x4 p = __builtin_nontemporal_load(
      reinterpret_cast<const f32x4*>(pts) + i);

  // exact numpy-f32 sequence: (p + 1.0f) * scale - 0.5f  (no contraction)
  float xf = (p.x + 1.0f) * scale - 0.5f;
  float yf = (p.y + 1.0f) * scale - 0.5f;
  float zf = (p.z + 1.0f) * scale - 0.5f;
  float xi = floorf(xf), yi = floorf(yf), zi = floorf(zf);
  float fx = xf - xi, fy = yf - yi, fz = zf - zi;

  // grid row order: corner = (gx<<2)|(gy<<1)|gz
  int gx = (l >> 2) & 1, gy = (l >> 1) & 1, gz = l & 1;
  unsigned ux = ((unsigned)((int)xi + gx)) & cmask;
  unsigned uy = ((unsigned)((int)yi + gy)) & cmask;
  unsigned uz = ((unsigned)((int)zi + gz)) & cmask;
  int b = (int)p.w;

  int key = (int)((morton_spread(ux) << 2) | (morton_spread(uy) << 1) |
                  morton_spread(uz)) | (b << (3 * depth));

  // bucket-accelerated searchsorted (side=left)
  unsigned bkt = ((unsigned)key) >> S;
  int lo = tab[bkt];
  int hi = tab[bkt + 1];
  bool present = false;
  int posc = 0;
  if (lo < hi) {                    // bucket non-empty (~61%)
    int hi0 = hi;
    while (lo < hi) {               // <=5 steps over a <=32-key bucket
      int mid = (lo + hi) >> 1;
      if (keys[mid] < key) lo = mid + 1; else hi = mid;
    }
    present = (lo < hi0) && (keys[lo] == key);
    posc = lo;
  }

  // trilinear weight |((1-gx)-fx) * ((1-gy)-fy) * ((1-gz)-fz)|
  float wx = (1.0f - (float)gx) - fx;
  float wy = (1.0f - (float)gy) - fy;
  float wz = (1.0f - (float)gz) - fz;
  float w = present ? fabsf((wx * wy) * wz) : 0.0f;

  // exchange (w, pos) across the aligned 8-lane group; accumulate float4
  int lane = threadIdx.x & 63;
  int base = lane & 56;
  float4 acc = make_float4(0.f, 0.f, 0.f, 0.f);
  float norm = 0.0f;
  #pragma unroll
  for (int q = 0; q < 8; ++q) {
    float wq = __shfl(w, base + q, 64);
    int   pq = __shfl(posc, base + q, 64);
    norm += wq;
    if (wq != 0.0f) {  // skip gather when weight is exactly 0 (identical math)
      float4 f = reinterpret_cast<const float4*>(data)[pq * 8 + l];
      acc.x += wq * f.x;
      acc.y += wq * f.y;
      acc.z += wq * f.z;
      acc.w += wq * f.w;
    }
  }
  float dnm = norm + 1e-12f;
  f32x4 o = {acc.x / dnm, acc.y / dnm, acc.z / dnm, acc.w / dnm};
  // streaming write: non-temporal, don't evict keys/tab from L2
  __builtin_nontemporal_store(o, reinterpret_cast<f32x4*>(out) + i * 8 + l);
}

// ---------------------------------------------------------------------------
// Generic-C fallback (defensive; reference uses C=32 so this should not run)
// ---------------------------------------------------------------------------
__global__ __launch_bounds__(256) void octi_interp_gen(
    const float* __restrict__ data, const float* __restrict__ pts,
    const int* __restrict__ keys, const int* __restrict__ depth_ptr,
    const int* __restrict__ tab, float* __restrict__ out,
    int N, int H, int C, int kbits) {
  int i = blockIdx.x * 256 + threadIdx.x;
  if (i >= N) return;
  int depth = *depth_ptr;
  int kb = 3 * depth + 2;
  int S = kb > kbits ? kb - kbits : 0;
  float scale = (float)(1 << (depth - 1));
  unsigned cmask = (1u << depth) - 1u;
  const float4 p = reinterpret_cast<const float4*>(pts)[i];
  float xf = (p.x + 1.0f) * scale - 0.5f;
  float yf = (p.y + 1.0f) * scale - 0.5f;
  float zf = (p.z + 1.0f) * scale - 0.5f;
  float xi = floorf(xf), yi = floorf(yf), zi = floorf(zf);
  float fx = xf - xi, fy = yf - yi, fz = zf - zi;
  int b = (int)p.w;
  float wv[8]; int pv[8];
  float norm = 0.0f;
  for (int l = 0; l < 8; ++l) {
    int gx = (l >> 2) & 1, gy = (l >> 1) & 1, gz = l & 1;
    unsigned ux = ((unsigned)((int)xi + gx)) & cmask;
    unsigned uy = ((unsigned)((int)yi + gy)) & cmask;
    unsigned uz = ((unsigned)((int)zi + gz)) & cmask;
    int key = (int)((morton_spread(ux) << 2) | (morton_spread(uy) << 1) |
                    morton_spread(uz)) | (b << (3 * depth));
    unsigned bkt = ((unsigned)key) >> S;
    int lo = tab ? tab[bkt] : 0;
    int hi = tab ? tab[bkt + 1] : H;
    bool present = false; int posc = 0;
    if (lo < hi) {
      int hi0 = hi;
      while (lo < hi) { int mid = (lo + hi) >> 1; if (keys[mid] < key) lo = mid + 1; else hi = mid; }
      present = (lo < hi0) && (keys[lo] == key);
      posc = lo;
    }
    float wx = (1.0f - (float)gx) - fx;
    float wy = (1.0f - (float)gy) - fy;
    float wz = (1.0f - (float)gz) - fz;
    float w = present ? fabsf((wx * wy) * wz) : 0.0f;
    wv[l] = w; pv[l] = posc; norm += w;
  }
  float dnm = norm + 1e-12f;
  for (int c = 0; c < C; ++c) {
    float acc = 0.0f;
    for (int q = 0; q < 8; ++q)
      if (wv[q] != 0.0f) acc += wv[q] * data[(long long)pv[q] * C + c];
    out[(long long)i * C + c] = acc / dnm;
  }
}

extern "C" void kernel_launch(void* const* d_in, const int* in_sizes, int n_in,
                              void* d_out, int out_size, void* d_ws, size_t ws_size,
                              hipStream_t stream) {
  const float* data = (const float*)d_in[0];
  const float* pts  = (const float*)d_in[1];
  const int*   keys = (const int*)d_in[2];
  const int*   dep  = (const int*)d_in[3];
  float* out = (float*)d_out;

  int H = in_sizes[2];
  int N = in_sizes[1] / 4;
  int C = (H > 0) ? in_sizes[0] / H : 0;

  // pick the largest bucket table that fits the workspace
  int kbits = K_BITS_BIG;
  if (ws_size < ((size_t)(1 << kbits) + 1) * sizeof(int)) kbits = K_BITS;
  int NB1 = (1 << kbits) + 1;
  bool useTab = ws_size >= (size_t)NB1 * sizeof(int);
  int* tab = (int*)d_ws;

  if (useTab) {
    octi_init<<<(NB1 + 255) / 256, 256, 0, stream>>>(tab, NB1, H);
    octi_scatter<<<(H + 255) / 256, 256, 0, stream>>>(keys, H, dep, tab, kbits);
  }

  if (C == 32 && useTab) {
    long long tt = (long long)N * 8;
    int blocks = (int)((tt + 255) / 256);
    octi_interp32<<<blocks, 256, 0, stream>>>(
        data, pts, keys, dep, tab, out, N, H, kbits);
  } else {
    int blocks = (N + 255) / 256;
    octi_interp_gen<<<blocks, 256, 0, stream>>>(
        data, pts, keys, dep, useTab ? tab : nullptr, out, N, H, C, kbits);
  }
}